// Round 3
// baseline (367.371 us; speedup 1.0000x reference)
//
#include <hip/hip_runtime.h>

#define THRESH 1.0f

typedef float f4 __attribute__((ext_vector_type(4)));

// ---------------------------------------------------------------------------
// Kernel 1: per-edge "any batch exceeds threshold" flags.
// Edge e in [0,1984):
//   e <  992 : h-edge, i=e/31, j=e%31, between cells (i,j) and (i,j+1)
//   e >= 992 : v-edge, e2=e-992, i=e2>>5, j=e2&31, between (i,j) and (i+1,j)
// One block (192 threads = 3 waves = 192 float4 lanes) per edge; loops over
// batches with early exit once exceeded (sqrt(s)>1 <=> s>1, monotone sum).
// With N(0,1) inputs E[s] ~ 1536 >> 1, so this exits at b=0 and reads only
// ~12 MB logical — but remains correct for arbitrary inputs.
// ---------------------------------------------------------------------------
__global__ __launch_bounds__(192) void edge_flags_kernel(
    const float* __restrict__ x, int* __restrict__ flags) {
  __shared__ float red[3];
  __shared__ int sdone;
  const int e = blockIdx.x;
  const int t = threadIdx.x;
  if (t == 0) sdone = 0;
  __syncthreads();

  int p0, p1;
  if (e < 992) {
    int i = e / 31; int j = e - i * 31;
    p0 = i * 32 + j; p1 = p0 + 1;
  } else {
    int e2 = e - 992; int i = e2 >> 5; int j = e2 & 31;
    p0 = i * 32 + j; p1 = p0 + 32;
  }

  const int lane = t & 63;
  const int wid  = t >> 6;

  for (int b = 0; b < 64; ++b) {
    const f4* A = (const f4*)(x + ((size_t)b * 1024 + p0) * 768);
    const f4* B = (const f4*)(x + ((size_t)b * 1024 + p1) * 768);
    f4 d = A[t] - B[t];
    float s = d.x * d.x + d.y * d.y + d.z * d.z + d.w * d.w;
#pragma unroll
    for (int off = 32; off > 0; off >>= 1) s += __shfl_down(s, off, 64);
    if (lane == 0) red[wid] = s;
    __syncthreads();
    if (t == 0) {
      float tot = red[0] + red[1] + red[2];
      if (tot > THRESH) sdone = 1;
    }
    __syncthreads();
    if (sdone) break;  // block-uniform (shared var after barrier)
  }
  if (t == 0) flags[e] = sdone;
}

// ---------------------------------------------------------------------------
// Kernel 2: apply. One block per (b, i) row-strip: 32 cells x 768 floats
// = 6144 float4; 256 threads x 24 float4 each.
//  - left/right neighbors are inside the block's own strip -> L1 reuse
//  - up/down are strips i+-1: with the XCD swizzle (xcd = blockIdx & 7
//    round-robin heuristic), all consumers of a strip run on one XCD's L2,
//    and the whole 2048-block grid is co-resident (8 blk/CU x 4 waves).
//  - 24 independent iterations/thread -> deep memory-level parallelism.
//  - nontemporal stores: `out` is never re-read; keep L2 for input reuse.
// Mask for the block's 32 cells is built in LDS from the 4 edge flags.
// ---------------------------------------------------------------------------
__global__ __launch_bounds__(256) void apply_kernel(
    const float* __restrict__ x, const int* __restrict__ flags,
    float* __restrict__ out) {
  __shared__ int mask_lds[32];
  const int p    = blockIdx.x;
  const int xcd  = p & 7;
  const int slot = p >> 3;                 // 0..255
  const int b    = (xcd << 3) | (slot >> 5);  // xcd owns 8 whole batches
  const int i    = slot & 31;
  const int t    = threadIdx.x;

  if (t < 32) {
    int j = t, m = 0;
    if (i >= 1 && i <= 30 && j >= 1 && j <= 30) {
      const int* fh = flags;        // [32][31]
      const int* fv = flags + 992;  // [31][32]
      m = fh[i * 31 + (j - 1)] | fh[i * 31 + j] |
          fv[(i - 1) * 32 + j] | fv[i * 32 + j];
    }
    mask_lds[j] = m;
  }
  __syncthreads();

  const f4* xv = (const f4*)x;
  f4* ov = (f4*)out;
  const size_t base = ((size_t)b * 1024 + (size_t)i * 32) * 192;

#pragma unroll 8
  for (int it = 0; it < 24; ++it) {
    const int idx = t + it * 256;          // 0..6143 within strip
    const int j   = (unsigned)idx / 192u;  // compiler magic-mul
    const size_t e = base + idx;
    f4 c = xv[e];
    if (mask_lds[j]) {
      f4 l = xv[e - 192];     // j-1
      f4 r = xv[e + 192];     // j+1
      f4 u = xv[e - 6144];    // i-1
      f4 d = xv[e + 6144];    // i+1
      f4 res = 0.5f * c + 0.125f * ((l + r) + (u + d));
      __builtin_nontemporal_store(res, &ov[e]);
    } else {
      __builtin_nontemporal_store(c, &ov[e]);
    }
  }
}

extern "C" void kernel_launch(void* const* d_in, const int* in_sizes, int n_in,
                              void* d_out, int out_size, void* d_ws,
                              size_t ws_size, hipStream_t stream) {
  const float* x = (const float*)d_in[0];
  float* out = (float*)d_out;
  int* flags = (int*)d_ws;  // 1984 ints

  edge_flags_kernel<<<1984, 192, 0, stream>>>(x, flags);
  apply_kernel<<<64 * 32, 256, 0, stream>>>(x, flags, out);
}